// Round 3
// baseline (463.456 us; speedup 1.0000x reference)
//
#include <hip/hip_runtime.h>
#include <math.h>

// Problem constants
#define BB 8
#define HH 1024
#define WW 1024
#define HW (1024*1024)

#define TW 128         // tile width (output px)
#define TH 16          // tile height
#define HALO_H (TH+6)  // 22
#define TSTRIDE 136    // byte tile row stride; stored_col = halo_col + 1
#define NCOPY 32
#define NSLOT 18       // per image: [0]=focal, [1]=edge, [2+b]=I_b, [10+b]=U_b
#define NBLOCKS (8*64*8)
// acc layout: acc[(img*NSLOT + slot)*NCOPY + copy]; counter after 54*NCOPY doubles

__global__ __launch_bounds__(256, 8)
void loss_main(const float* __restrict__ pred,
               const float* __restrict__ diss,
               const int*   __restrict__ target,
               double*      __restrict__ acc,
               const float* __restrict__ diff,
               const float* __restrict__ sigma,
               float*       __restrict__ out)
{
    __shared__ unsigned char tileb[HALO_H][TSTRIDE];  // 2992 B (target 0/1)
    __shared__ unsigned char h5b[HALO_H][TW];         // 2816 B (5-wide sums, <=5)
    __shared__ unsigned char h7b[HALO_H][TW];         // 2816 B (7-wide sums, <=7)
    __shared__ float red[4][12];
    __shared__ double ssum[54];
    __shared__ int lastflag;

    const int bx = blockIdx.x;   // 0..7
    const int by = blockIdx.y;   // 0..63
    const int b  = blockIdx.z;   // 0..7
    const int x0 = bx * TW, y0 = by * TH;
    const int tid = threadIdx.x;
    const int txx = tid & 31;    // x-group of 4 px
    const int ty  = tid >> 5;    // 0..7

    // ---- stage 1: target halo -> packed bytes in LDS ----
    const int* tgt_b = target + (size_t)b * HW;
    for (int ch = tid; ch < HALO_H * 34; ch += 256) {
        int r = ch / 34;
        int m = ch - r * 34;
        int gy  = y0 - 3 + r;
        int gxb = x0 - 4 + 4 * m;     // stored cols 4m..4m+3
        unsigned pk = 0u;
        if (gy >= 0 && gy < HH) {
            if (gxb >= 0 && gxb + 3 < WW) {
                const int4 iv = *(const int4*)(tgt_b + (size_t)gy * WW + gxb);
                pk = (unsigned)iv.x | ((unsigned)iv.y << 8)
                   | ((unsigned)iv.z << 16) | ((unsigned)iv.w << 24);
            } else {
                #pragma unroll
                for (int j = 0; j < 4; ++j) {
                    int gx = gxb + j;
                    if (gx >= 0 && gx < WW)
                        pk |= ((unsigned)tgt_b[(size_t)gy * WW + gx]) << (8 * j);
                }
            }
        }
        *(unsigned*)&tileb[r][4 * m] = pk;
    }
    __syncthreads();

    // ---- stage 2: horizontal 5/7-wide sums, packed bytes ----
    for (int g = tid; g < HALO_H * 32; g += 256) {
        int r  = g >> 5;
        int xg = (g & 31) << 2;
        const unsigned char* row = &tileb[r][0];
        unsigned d0 = *(const unsigned*)(row + xg);       // stored x..x+3
        unsigned d1 = *(const unsigned*)(row + xg + 4);
        unsigned d2 = *(const unsigned*)(row + xg + 8);
        int s1 = (d0 >> 8) & 255, s2 = (d0 >> 16) & 255, s3 = (d0 >> 24) & 255;
        int s4 = d1 & 255, s5 = (d1 >> 8) & 255, s6 = (d1 >> 16) & 255, s7 = (d1 >> 24) & 255;
        int s8 = d2 & 255, s9 = (d2 >> 8) & 255, s10 = (d2 >> 16) & 255;
        int v5x = s2 + s3 + s4 + s5 + s6;
        int v5y = v5x - s2 + s7;
        int v5z = v5y - s3 + s8;
        int v5w = v5z - s4 + s9;
        int v7x = v5x + s1 + s7;
        int v7y = v5y + s2 + s8;
        int v7z = v5z + s3 + s9;
        int v7w = v5w + s4 + s10;
        *(unsigned*)&h5b[r][xg] = (unsigned)v5x | ((unsigned)v5y << 8)
                                | ((unsigned)v5z << 16) | ((unsigned)v5w << 24);
        *(unsigned*)&h7b[r][xg] = (unsigned)v7x | ((unsigned)v7y << 8)
                                | ((unsigned)v7z << 16) | ((unsigned)v7w << 24);
    }
    __syncthreads();

    // ---- stage 3: fused per-pixel terms, 4 px/thread, 3 images ----
    const float* p00 = pred + ((size_t)(0 * BB + b) * 2 + 0) * HW;
    const float* p01 = p00 + HW;
    const float* p10 = pred + ((size_t)(1 * BB + b) * 2 + 0) * HW;
    const float* p11 = p10 + HW;
    const float* q0  = diss + ((size_t)b * 2 + 0) * HW;
    const float* q1  = q0 + HW;

    float sf0=0.f, se0=0.f, si0=0.f, su0=0.f;
    float sf1=0.f, se1=0.f, si1=0.f, su1=0.f;
    float sf2=0.f, se2=0.f, si2=0.f, su2=0.f;

    const int x  = txx * 4;
    const int gx = x0 + x;
    #pragma unroll
    for (int k = 0; k < 2; ++k) {
        const int r  = ty + 8 * k;       // 0..15
        const int gy = y0 + r;
        const size_t off = (size_t)gy * WW + gx;

        const unsigned tq  = *(const unsigned*)&tileb[r + 3][x + 4];
        const unsigned top = *(const unsigned*)&tileb[r    ][x + 4];
        const unsigned bot = *(const unsigned*)&tileb[r + 6][x + 4];
        const unsigned c1  = *(const unsigned*)&h5b[r + 1][x];
        const unsigned c2  = *(const unsigned*)&h5b[r + 2][x];
        const unsigned c3  = *(const unsigned*)&h7b[r + 3][x];
        const unsigned c4  = *(const unsigned*)&h5b[r + 4][x];
        const unsigned c5  = *(const unsigned*)&h5b[r + 5][x];
        // byte-lane sums: max 29 per byte, no carry into next byte
        const unsigned cnt = top + bot + c1 + c2 + c3 + c4 + c5;

        const float4 v00 = *(const float4*)(p00 + off);
        const float4 v01 = *(const float4*)(p01 + off);
        const float4 v10 = *(const float4*)(p10 + off);
        const float4 v11 = *(const float4*)(p11 + off);
        const float4 w0  = *(const float4*)(q0  + off);
        const float4 w1  = *(const float4*)(q1  + off);

        #pragma unroll
        for (int j = 0; j < 4; ++j) {
            const unsigned tbit = (tq >> (8 * j)) & 1u;
            const float tf = (float)tbit;
            const float cj = (float)((cnt >> (8 * j)) & 0xffu);
            const float at = fabsf(tf - cj * (1.0f / 29.0f));
            // image 0 (softmax of 2 channels)
            {
                float a0 = ((const float*)&v00)[j], a1 = ((const float*)&v01)[j];
                float p1v = __builtin_amdgcn_rcpf(1.0f + __expf(a0 - a1));
                float pt  = tbit ? p1v : 1.0f - p1v;
                float lp  = __logf(pt + 1e-10f);
                sf0 -= lp; se0 -= lp * at; si0 += p1v * tf; su0 += p1v + tf;
            }
            // image 1
            {
                float a0 = ((const float*)&v10)[j], a1 = ((const float*)&v11)[j];
                float p1v = __builtin_amdgcn_rcpf(1.0f + __expf(a0 - a1));
                float pt  = tbit ? p1v : 1.0f - p1v;
                float lp  = __logf(pt + 1e-10f);
                sf1 -= lp; se1 -= lp * at; si1 += p1v * tf; su1 += p1v + tf;
            }
            // Diss (raw probs)
            {
                float d0 = ((const float*)&w0)[j], d1 = ((const float*)&w1)[j];
                float pt = tbit ? d1 : d0;
                float lp = __logf(pt + 1e-10f);
                sf2 -= lp; se2 -= lp * at; si2 += d1 * tf; su2 += d1 + tf;
            }
        }
    }

    // ---- stage 4: block reduction -> 12 f64 atomics ----
    float vals[12] = {sf0,se0,si0,su0, sf1,se1,si1,su1, sf2,se2,si2,su2};
    #pragma unroll
    for (int j = 0; j < 12; ++j) {
        float v = vals[j];
        #pragma unroll
        for (int s = 32; s > 0; s >>= 1) v += __shfl_down(v, s, 64);
        vals[j] = v;
    }
    const int wave = tid >> 6;
    const int lane = tid & 63;
    if (lane == 0) {
        #pragma unroll
        for (int j = 0; j < 12; ++j) red[wave][j] = vals[j];
    }
    __syncthreads();
    if (tid < 12) {
        double s = (double)red[0][tid] + (double)red[1][tid]
                 + (double)red[2][tid] + (double)red[3][tid];
        const int img  = tid >> 2;
        const int what = tid & 3;
        int slot;
        if      (what == 0) slot = 0;
        else if (what == 1) slot = 1;
        else if (what == 2) slot = 2 + b;
        else                slot = 10 + b;
        const int copy = (by * 8 + bx) & (NCOPY - 1);
        unsafeAtomicAdd(acc + ((size_t)(img * NSLOT + slot) * NCOPY + copy), s);
    }
    __syncthreads();   // waves drain their atomics (vmcnt(0)) before counting

    // ---- stage 5: last block finalizes ----
    unsigned* counter = (unsigned*)(acc + 54 * NCOPY);
    if (tid == 0) {
        __threadfence();
        unsigned old = atomicAdd(counter, 1u);
        lastflag = (old == NBLOCKS - 1) ? 1 : 0;
    }
    __syncthreads();
    if (lastflag) {
        __threadfence();
        if (tid < 216) {
            const int sl = tid >> 2, part = tid & 3;
            const double* p = acc + (size_t)sl * NCOPY + part * 8;
            double s = 0.0;
            #pragma unroll
            for (int j = 0; j < 8; ++j)
                s += __hip_atomic_load(&p[j], __ATOMIC_RELAXED, __HIP_MEMORY_SCOPE_AGENT);
            s += __shfl_down(s, 1, 64);
            s += __shfl_down(s, 2, 64);
            if (part == 0) ssum[sl] = s;
        }
        __syncthreads();
        if (tid == 0) {
            const double sig0 = (double)sigma[0] * (double)sigma[0];
            const double sig1 = (double)sigma[1] * (double)sigma[1];
            const double sig2 = (double)sigma[2] * (double)sigma[2];
            const double inv  = 1.0 / (double)((size_t)BB * HW);
            double loss = 0.0;
            for (int i = 0; i < 3; ++i) {
                const double* A = ssum + i * NSLOT;
                double focal = A[0] * inv;
                double edge  = A[1] * inv;
                double dsum  = 0.0;
                for (int bb = 0; bb < BB; ++bb)
                    dsum += 2.0 * A[2 + bb] / (A[10 + bb] + 1e-10);
                double dice = 1.0 - dsum / (double)BB;
                loss += focal / sig0 + dice / sig1 + edge / sig2;
            }
            loss += (double)diff[0];
            loss += 0.5 * (log(sig0) + log(sig1) + log(sig2));
            out[0] = (float)loss;
        }
    }
}

extern "C" void kernel_launch(void* const* d_in, const int* in_sizes, int n_in,
                              void* d_out, int out_size, void* d_ws, size_t ws_size,
                              hipStream_t stream)
{
    const float* pred   = (const float*)d_in[0]; // (2,8,2,1024,1024)
    const float* diss   = (const float*)d_in[1]; // (1,8,2,1024,1024)
    const int*   target = (const int*)  d_in[2]; // (8,1024,1024)
    const float* diff   = (const float*)d_in[3];
    const float* sigma  = (const float*)d_in[4];
    double* acc = (double*)d_ws;

    // zero accumulators + last-block counter
    hipMemsetAsync(d_ws, 0, (size_t)54 * NCOPY * sizeof(double) + 16, stream);

    dim3 grid(WW / TW, HH / TH, BB);   // (8, 64, 8) = 4096 blocks
    loss_main<<<grid, 256, 0, stream>>>(pred, diss, target, acc, diff, sigma,
                                        (float*)d_out);
}

// Round 4
// 366.771 us; speedup vs baseline: 1.2636x; 1.2636x over previous
//
#include <hip/hip_runtime.h>
#include <math.h>

// Problem constants
#define BB 8
#define HH 1024
#define WW 1024
#define HW (1024*1024)

#define TW 128         // tile width (output px)
#define TH 32          // tile height
#define HALO_H (TH+6)  // 38
#define TSTRIDE 136    // byte tile row stride; stored_col = halo_col + 1
#define NCOPY 32
#define NSLOT 18       // per image: [0]=focal, [1]=edge, [2+b]=I_b, [10+b]=U_b
#define NBLOCKS (8*32*8)   // 2048 blocks = exactly 8 per CU
// acc layout: acc[(img*NSLOT + slot)*NCOPY + copy]; counter after 54*NCOPY doubles

__global__ __launch_bounds__(256, 4)
void loss_main(const float* __restrict__ pred,
               const float* __restrict__ diss,
               const int*   __restrict__ target,
               double*      __restrict__ acc,
               const float* __restrict__ diff,
               const float* __restrict__ sigma,
               float*       __restrict__ out)
{
    __shared__ unsigned char tileb[HALO_H][TSTRIDE];  // 5168 B (target 0/1)
    __shared__ unsigned char h5b[HALO_H][TW];         // 4864 B
    __shared__ unsigned char h7b[HALO_H][TW];         // 4864 B
    __shared__ float red[4][12];
    __shared__ double ssum[54];
    __shared__ int lastflag;

    const int bx = blockIdx.x;   // 0..7
    const int by = blockIdx.y;   // 0..31
    const int b  = blockIdx.z;   // 0..7
    const int x0 = bx * TW, y0 = by * TH;
    const int tid = threadIdx.x;
    const int txx = tid & 31;    // x-group of 4 px
    const int ty  = tid >> 5;    // 0..7

    // ---- stage 1: target halo -> packed bytes in LDS ----
    const int* tgt_b = target + (size_t)b * HW;
    for (int ch = tid; ch < HALO_H * 34; ch += 256) {
        int r = ch / 34;
        int m = ch - r * 34;
        int gy  = y0 - 3 + r;
        int gxb = x0 - 4 + 4 * m;     // stored cols 4m..4m+3
        unsigned pk = 0u;
        if (gy >= 0 && gy < HH) {
            if (gxb >= 0 && gxb + 3 < WW) {
                const int4 iv = *(const int4*)(tgt_b + (size_t)gy * WW + gxb);
                pk = (unsigned)iv.x | ((unsigned)iv.y << 8)
                   | ((unsigned)iv.z << 16) | ((unsigned)iv.w << 24);
            } else {
                #pragma unroll
                for (int j = 0; j < 4; ++j) {
                    int gx = gxb + j;
                    if (gx >= 0 && gx < WW)
                        pk |= ((unsigned)tgt_b[(size_t)gy * WW + gx]) << (8 * j);
                }
            }
        }
        *(unsigned*)&tileb[r][4 * m] = pk;
    }
    __syncthreads();

    // ---- stage 2: horizontal 5/7-wide sums, packed bytes ----
    for (int g = tid; g < HALO_H * 32; g += 256) {
        int r  = g >> 5;
        int xg = (g & 31) << 2;
        const unsigned char* row = &tileb[r][0];
        unsigned d0 = *(const unsigned*)(row + xg);       // stored x..x+3
        unsigned d1 = *(const unsigned*)(row + xg + 4);
        unsigned d2 = *(const unsigned*)(row + xg + 8);
        int s1 = (d0 >> 8) & 255, s2 = (d0 >> 16) & 255, s3 = (d0 >> 24) & 255;
        int s4 = d1 & 255, s5 = (d1 >> 8) & 255, s6 = (d1 >> 16) & 255, s7 = (d1 >> 24) & 255;
        int s8 = d2 & 255, s9 = (d2 >> 8) & 255, s10 = (d2 >> 16) & 255;
        int v5x = s2 + s3 + s4 + s5 + s6;
        int v5y = v5x - s2 + s7;
        int v5z = v5y - s3 + s8;
        int v5w = v5z - s4 + s9;
        int v7x = v5x + s1 + s7;
        int v7y = v5y + s2 + s8;
        int v7z = v5z + s3 + s9;
        int v7w = v5w + s4 + s10;
        *(unsigned*)&h5b[r][xg] = (unsigned)v5x | ((unsigned)v5y << 8)
                                | ((unsigned)v5z << 16) | ((unsigned)v5w << 24);
        *(unsigned*)&h7b[r][xg] = (unsigned)v7x | ((unsigned)v7y << 8)
                                | ((unsigned)v7z << 16) | ((unsigned)v7w << 24);
    }
    __syncthreads();

    // ---- stage 3: fused per-pixel terms, 16 px/thread, software-pipelined ----
    const float* p00 = pred + ((size_t)(0 * BB + b) * 2 + 0) * HW;
    const float* p01 = p00 + HW;
    const float* p10 = pred + ((size_t)(1 * BB + b) * 2 + 0) * HW;
    const float* p11 = p10 + HW;
    const float* q0  = diss + ((size_t)b * 2 + 0) * HW;
    const float* q1  = q0 + HW;

    float sf0=0.f, se0=0.f, si0=0.f, su0=0.f;
    float sf1=0.f, se1=0.f, si1=0.f, su1=0.f;
    float sf2=0.f, se2=0.f, si2=0.f, su2=0.f;

    const int x  = txx * 4;
    const int gx = x0 + x;
    size_t off = (size_t)(y0 + ty) * WW + gx;

    // prime the pipeline (k = 0)
    float4 c00 = *(const float4*)(p00 + off);
    float4 c01 = *(const float4*)(p01 + off);
    float4 c10 = *(const float4*)(p10 + off);
    float4 c11 = *(const float4*)(p11 + off);
    float4 cw0 = *(const float4*)(q0  + off);
    float4 cw1 = *(const float4*)(q1  + off);

    #pragma unroll
    for (int k = 0; k < 4; ++k) {
        float4 n00, n01, n10, n11, nw0, nw1;
        if (k < 3) {
            const size_t offn = off + (size_t)8 * WW;
            n00 = *(const float4*)(p00 + offn);
            n01 = *(const float4*)(p01 + offn);
            n10 = *(const float4*)(p10 + offn);
            n11 = *(const float4*)(p11 + offn);
            nw0 = *(const float4*)(q0  + offn);
            nw1 = *(const float4*)(q1  + offn);
            off = offn;
        }

        const int r = ty + 8 * k;        // 0..31
        const unsigned tq  = *(const unsigned*)&tileb[r + 3][x + 4];
        const unsigned top = *(const unsigned*)&tileb[r    ][x + 4];
        const unsigned bot = *(const unsigned*)&tileb[r + 6][x + 4];
        const unsigned e1  = *(const unsigned*)&h5b[r + 1][x];
        const unsigned e2  = *(const unsigned*)&h5b[r + 2][x];
        const unsigned e3  = *(const unsigned*)&h7b[r + 3][x];
        const unsigned e4  = *(const unsigned*)&h5b[r + 4][x];
        const unsigned e5  = *(const unsigned*)&h5b[r + 5][x];
        // byte-lane sums: max 29 per byte, no carry into next byte
        const unsigned cnt = top + bot + e1 + e2 + e3 + e4 + e5;

        #pragma unroll
        for (int j = 0; j < 4; ++j) {
            const unsigned tbit = (tq >> (8 * j)) & 1u;
            const float tf = (float)tbit;
            const float cj = (float)((cnt >> (8 * j)) & 0xffu);
            const float at = fabsf(tf - cj * (1.0f / 29.0f));
            // image 0 (softmax of 2 channels)
            {
                float a0 = ((const float*)&c00)[j], a1 = ((const float*)&c01)[j];
                float p1v = __builtin_amdgcn_rcpf(1.0f + __expf(a0 - a1));
                float pt  = tbit ? p1v : 1.0f - p1v;
                float lp  = __logf(pt + 1e-10f);
                sf0 -= lp; se0 -= lp * at; si0 += p1v * tf; su0 += p1v + tf;
            }
            // image 1
            {
                float a0 = ((const float*)&c10)[j], a1 = ((const float*)&c11)[j];
                float p1v = __builtin_amdgcn_rcpf(1.0f + __expf(a0 - a1));
                float pt  = tbit ? p1v : 1.0f - p1v;
                float lp  = __logf(pt + 1e-10f);
                sf1 -= lp; se1 -= lp * at; si1 += p1v * tf; su1 += p1v + tf;
            }
            // Diss (raw probs)
            {
                float d0 = ((const float*)&cw0)[j], d1 = ((const float*)&cw1)[j];
                float pt = tbit ? d1 : d0;
                float lp = __logf(pt + 1e-10f);
                sf2 -= lp; se2 -= lp * at; si2 += d1 * tf; su2 += d1 + tf;
            }
        }

        if (k < 3) {
            c00 = n00; c01 = n01; c10 = n10; c11 = n11; cw0 = nw0; cw1 = nw1;
        }
    }

    // ---- stage 4: block reduction -> 12 f64 atomics ----
    float vals[12] = {sf0,se0,si0,su0, sf1,se1,si1,su1, sf2,se2,si2,su2};
    #pragma unroll
    for (int j = 0; j < 12; ++j) {
        float v = vals[j];
        #pragma unroll
        for (int s = 32; s > 0; s >>= 1) v += __shfl_down(v, s, 64);
        vals[j] = v;
    }
    const int wave = tid >> 6;
    const int lane = tid & 63;
    if (lane == 0) {
        #pragma unroll
        for (int j = 0; j < 12; ++j) red[wave][j] = vals[j];
    }
    __syncthreads();
    if (tid < 12) {
        double s = (double)red[0][tid] + (double)red[1][tid]
                 + (double)red[2][tid] + (double)red[3][tid];
        const int img  = tid >> 2;
        const int what = tid & 3;
        int slot;
        if      (what == 0) slot = 0;
        else if (what == 1) slot = 1;
        else if (what == 2) slot = 2 + b;
        else                slot = 10 + b;
        const int copy = (by * 8 + bx) & (NCOPY - 1);
        unsafeAtomicAdd(acc + ((size_t)(img * NSLOT + slot) * NCOPY + copy), s);
    }
    __syncthreads();   // drain atomics before counting

    // ---- stage 5: last block finalizes ----
    unsigned* counter = (unsigned*)(acc + 54 * NCOPY);
    if (tid == 0) {
        __threadfence();
        unsigned old = atomicAdd(counter, 1u);
        lastflag = (old == NBLOCKS - 1) ? 1 : 0;
    }
    __syncthreads();
    if (lastflag) {
        __threadfence();
        if (tid < 216) {
            const int sl = tid >> 2, part = tid & 3;
            const double* p = acc + (size_t)sl * NCOPY + part * 8;
            double s = 0.0;
            #pragma unroll
            for (int j = 0; j < 8; ++j)
                s += __hip_atomic_load(&p[j], __ATOMIC_RELAXED, __HIP_MEMORY_SCOPE_AGENT);
            s += __shfl_down(s, 1, 64);
            s += __shfl_down(s, 2, 64);
            if (part == 0) ssum[sl] = s;
        }
        __syncthreads();
        if (tid == 0) {
            const double sig0 = (double)sigma[0] * (double)sigma[0];
            const double sig1 = (double)sigma[1] * (double)sigma[1];
            const double sig2 = (double)sigma[2] * (double)sigma[2];
            const double inv  = 1.0 / (double)((size_t)BB * HW);
            double loss = 0.0;
            for (int i = 0; i < 3; ++i) {
                const double* A = ssum + i * NSLOT;
                double focal = A[0] * inv;
                double edge  = A[1] * inv;
                double dsum  = 0.0;
                for (int bb = 0; bb < BB; ++bb)
                    dsum += 2.0 * A[2 + bb] / (A[10 + bb] + 1e-10);
                double dice = 1.0 - dsum / (double)BB;
                loss += focal / sig0 + dice / sig1 + edge / sig2;
            }
            loss += (double)diff[0];
            loss += 0.5 * (log(sig0) + log(sig1) + log(sig2));
            out[0] = (float)loss;
        }
    }
}

extern "C" void kernel_launch(void* const* d_in, const int* in_sizes, int n_in,
                              void* d_out, int out_size, void* d_ws, size_t ws_size,
                              hipStream_t stream)
{
    const float* pred   = (const float*)d_in[0]; // (2,8,2,1024,1024)
    const float* diss   = (const float*)d_in[1]; // (1,8,2,1024,1024)
    const int*   target = (const int*)  d_in[2]; // (8,1024,1024)
    const float* diff   = (const float*)d_in[3];
    const float* sigma  = (const float*)d_in[4];
    double* acc = (double*)d_ws;

    // zero accumulators + last-block counter
    hipMemsetAsync(d_ws, 0, (size_t)54 * NCOPY * sizeof(double) + 16, stream);

    dim3 grid(WW / TW, HH / TH, BB);   // (8, 32, 8) = 2048 blocks
    loss_main<<<grid, 256, 0, stream>>>(pred, diss, target, acc, diff, sigma,
                                        (float*)d_out);
}

// Round 5
// 276.919 us; speedup vs baseline: 1.6736x; 1.3245x over previous
//
#include <hip/hip_runtime.h>
#include <math.h>

// Problem constants
#define BB 8
#define HH 1024
#define WW 1024
#define HW (1024*1024)

#define NCOPY 32
#define NSLOT 18       // per image: [0]=focal, [1]=edge, [2+b]=I_b, [10+b]=U_b
// acc layout: acc[(img*NSLOT + slot)*NCOPY + copy]
// d_ws layout: [0,13824) acc doubles; amap at byte offset 16384 (8 MB)

// ---------------- Pass A: target -> at-map (byte codes) ----------------
// code byte = (tbit << 7) | at29, where at29 = |29*t - cnt| in 0..29
#define TWA 128
#define THA 16
#define HALO_HA (THA + 6)   // 22
#define TSTRIDEA 136        // stored_col = halo_col + 1 (dword-aligned groups)

__global__ __launch_bounds__(256)
void at_map_kernel(const int* __restrict__ target,
                   unsigned char* __restrict__ amap)
{
    __shared__ unsigned char tileb[HALO_HA][TSTRIDEA];
    __shared__ unsigned char h5b[HALO_HA][TWA];
    __shared__ unsigned char h7b[HALO_HA][TWA];

    const int bx = blockIdx.x;   // 0..7
    const int by = blockIdx.y;   // 0..63
    const int b  = blockIdx.z;   // 0..7
    const int x0 = bx * TWA, y0 = by * THA;
    const int tid = threadIdx.x;

    // stage 1: target halo -> packed bytes
    const int* tgt_b = target + (size_t)b * HW;
    for (int ch = tid; ch < HALO_HA * 34; ch += 256) {
        int r = ch / 34;
        int m = ch - r * 34;
        int gy  = y0 - 3 + r;
        int gxb = x0 - 4 + 4 * m;    // stored cols 4m..4m+3
        unsigned pk = 0u;
        if (gy >= 0 && gy < HH) {
            if (gxb >= 0 && gxb + 3 < WW) {
                const int4 iv = *(const int4*)(tgt_b + (size_t)gy * WW + gxb);
                pk = (unsigned)iv.x | ((unsigned)iv.y << 8)
                   | ((unsigned)iv.z << 16) | ((unsigned)iv.w << 24);
            } else {
                #pragma unroll
                for (int j = 0; j < 4; ++j) {
                    int gx = gxb + j;
                    if (gx >= 0 && gx < WW)
                        pk |= ((unsigned)tgt_b[(size_t)gy * WW + gx]) << (8 * j);
                }
            }
        }
        *(unsigned*)&tileb[r][4 * m] = pk;
    }
    __syncthreads();

    // stage 2: horizontal 5/7-wide sums (byte lanes, max 7: no carry)
    for (int g = tid; g < HALO_HA * 32; g += 256) {
        int r  = g >> 5;
        int xg = (g & 31) << 2;
        const unsigned char* row = &tileb[r][0];
        unsigned d0 = *(const unsigned*)(row + xg);
        unsigned d1 = *(const unsigned*)(row + xg + 4);
        unsigned d2 = *(const unsigned*)(row + xg + 8);
        int s1 = (d0 >> 8) & 255, s2 = (d0 >> 16) & 255, s3 = (d0 >> 24) & 255;
        int s4 = d1 & 255, s5 = (d1 >> 8) & 255, s6 = (d1 >> 16) & 255, s7 = (d1 >> 24) & 255;
        int s8 = d2 & 255, s9 = (d2 >> 8) & 255, s10 = (d2 >> 16) & 255;
        int v5x = s2 + s3 + s4 + s5 + s6;
        int v5y = v5x - s2 + s7;
        int v5z = v5y - s3 + s8;
        int v5w = v5z - s4 + s9;
        int v7x = v5x + s1 + s7;
        int v7y = v5y + s2 + s8;
        int v7z = v5z + s3 + s9;
        int v7w = v5w + s4 + s10;
        *(unsigned*)&h5b[r][xg] = (unsigned)v5x | ((unsigned)v5y << 8)
                                | ((unsigned)v5z << 16) | ((unsigned)v5w << 24);
        *(unsigned*)&h7b[r][xg] = (unsigned)v7x | ((unsigned)v7y << 8)
                                | ((unsigned)v7z << 16) | ((unsigned)v7w << 24);
    }
    __syncthreads();

    // stage 3: per-pixel code bytes, 8 px/thread, dword stores
    const int x  = (tid & 31) * 4;
    const int gx = x0 + x;
    const int ty = tid >> 5;
    #pragma unroll
    for (int k = 0; k < 2; ++k) {
        const int r  = ty + 8 * k;      // 0..15
        const int gy = y0 + r;
        const unsigned tq  = *(const unsigned*)&tileb[r + 3][x + 4];
        const unsigned top = *(const unsigned*)&tileb[r    ][x + 4];
        const unsigned bot = *(const unsigned*)&tileb[r + 6][x + 4];
        const unsigned e1  = *(const unsigned*)&h5b[r + 1][x];
        const unsigned e2  = *(const unsigned*)&h5b[r + 2][x];
        const unsigned e3  = *(const unsigned*)&h7b[r + 3][x];
        const unsigned e4  = *(const unsigned*)&h5b[r + 4][x];
        const unsigned e5  = *(const unsigned*)&h5b[r + 5][x];
        const unsigned cnt = top + bot + e1 + e2 + e3 + e4 + e5;  // bytes <= 29

        unsigned code = 0u;
        #pragma unroll
        for (int j = 0; j < 4; ++j) {
            unsigned tbit = (tq >> (8 * j)) & 1u;
            int cj = (int)((cnt >> (8 * j)) & 0xffu);
            int a29 = tbit ? (29 - cj) : cj;      // |29*t - cnt|, 0..29
            code |= ((tbit << 7) | (unsigned)a29) << (8 * j);
        }
        *(unsigned*)(amap + (size_t)b * HW + (size_t)gy * WW + gx) = code;
    }
}

// ---------------- Pass B: pure streaming loss accumulation ----------------
// 2048 blocks x 256 threads; thread tg handles 4 px-groups in plane b = tg>>16
#define NITER 4

__global__ __launch_bounds__(256, 4)
void stream_kernel(const float* __restrict__ pred,
                   const float* __restrict__ diss,
                   const unsigned char* __restrict__ amap,
                   double* __restrict__ acc)
{
    __shared__ float red[4][12];

    const int tid = threadIdx.x;
    const unsigned tg = blockIdx.x * 256u + (unsigned)tid;  // 0..524287
    const int b = (int)(tg >> 16);                          // uniform per block
    const unsigned lane = tg & 65535u;

    const float* p00 = pred + ((size_t)(0 * BB + b) * 2 + 0) * HW;
    const float* p01 = p00 + HW;
    const float* p10 = pred + ((size_t)(1 * BB + b) * 2 + 0) * HW;
    const float* p11 = p10 + HW;
    const float* q0  = diss + ((size_t)b * 2 + 0) * HW;
    const float* q1  = q0 + HW;
    const unsigned char* am = amap + (size_t)b * HW;

    float sf0=0.f, se0=0.f, si0=0.f, su0=0.f;
    float sf1=0.f, se1=0.f, si1=0.f, su1=0.f;
    float sf2=0.f, se2=0.f, si2=0.f, su2=0.f;

    #pragma unroll
    for (int i = 0; i < NITER; ++i) {
        const size_t off = (size_t)lane * 4 + (size_t)i * (65536u * 4u); // px
        const unsigned  code = *(const unsigned*)(am + off);
        const float4 v00 = *(const float4*)(p00 + off);
        const float4 v01 = *(const float4*)(p01 + off);
        const float4 v10 = *(const float4*)(p10 + off);
        const float4 v11 = *(const float4*)(p11 + off);
        const float4 w0  = *(const float4*)(q0  + off);
        const float4 w1  = *(const float4*)(q1  + off);

        #pragma unroll
        for (int j = 0; j < 4; ++j) {
            const unsigned cj   = (code >> (8 * j)) & 0xffu;
            const unsigned tbit = cj >> 7;
            const float tf = (float)tbit;
            const float at = (float)(cj & 0x7fu) * (1.0f / 29.0f);
            // image 0 (softmax of 2 channels)
            {
                float a0 = ((const float*)&v00)[j], a1 = ((const float*)&v01)[j];
                float p1v = __builtin_amdgcn_rcpf(1.0f + __expf(a0 - a1));
                float pt  = tbit ? p1v : 1.0f - p1v;
                float lp  = __logf(pt + 1e-10f);
                sf0 -= lp; se0 -= lp * at; si0 += p1v * tf; su0 += p1v + tf;
            }
            // image 1
            {
                float a0 = ((const float*)&v10)[j], a1 = ((const float*)&v11)[j];
                float p1v = __builtin_amdgcn_rcpf(1.0f + __expf(a0 - a1));
                float pt  = tbit ? p1v : 1.0f - p1v;
                float lp  = __logf(pt + 1e-10f);
                sf1 -= lp; se1 -= lp * at; si1 += p1v * tf; su1 += p1v + tf;
            }
            // Diss (raw probs)
            {
                float d0 = ((const float*)&w0)[j], d1 = ((const float*)&w1)[j];
                float pt = tbit ? d1 : d0;
                float lp = __logf(pt + 1e-10f);
                sf2 -= lp; se2 -= lp * at; si2 += d1 * tf; su2 += d1 + tf;
            }
        }
    }

    // block reduction -> 12 f64 atomics
    float vals[12] = {sf0,se0,si0,su0, sf1,se1,si1,su1, sf2,se2,si2,su2};
    #pragma unroll
    for (int j = 0; j < 12; ++j) {
        float v = vals[j];
        #pragma unroll
        for (int s = 32; s > 0; s >>= 1) v += __shfl_down(v, s, 64);
        vals[j] = v;
    }
    const int wave = tid >> 6;
    const int lanew = tid & 63;
    if (lanew == 0) {
        #pragma unroll
        for (int j = 0; j < 12; ++j) red[wave][j] = vals[j];
    }
    __syncthreads();
    if (tid < 12) {
        double s = (double)red[0][tid] + (double)red[1][tid]
                 + (double)red[2][tid] + (double)red[3][tid];
        const int img  = tid >> 2;
        const int what = tid & 3;
        int slot;
        if      (what == 0) slot = 0;
        else if (what == 1) slot = 1;
        else if (what == 2) slot = 2 + b;
        else                slot = 10 + b;
        const int copy = blockIdx.x & (NCOPY - 1);
        unsafeAtomicAdd(acc + ((size_t)(img * NSLOT + slot) * NCOPY + copy), s);
    }
}

// ---------------- Pass C: parallel finalize ----------------
__global__ __launch_bounds__(256)
void finalize_kernel(const double* __restrict__ acc,
                     const float*  __restrict__ diff,
                     const float*  __restrict__ sigma,
                     float*        __restrict__ out)
{
    __shared__ double ssum[54];
    const int t = threadIdx.x;
    if (t < 216) {
        const int sl = t >> 2, part = t & 3;
        const double* p = acc + (size_t)sl * NCOPY + part * 8;
        double s = 0.0;
        #pragma unroll
        for (int j = 0; j < 8; ++j) s += p[j];
        s += __shfl_down(s, 1, 64);
        s += __shfl_down(s, 2, 64);
        if (part == 0) ssum[sl] = s;
    }
    __syncthreads();
    if (t == 0) {
        const double sig0 = (double)sigma[0] * (double)sigma[0];
        const double sig1 = (double)sigma[1] * (double)sigma[1];
        const double sig2 = (double)sigma[2] * (double)sigma[2];
        const double inv  = 1.0 / (double)((size_t)BB * HW);
        double loss = 0.0;
        for (int i = 0; i < 3; ++i) {
            const double* A = ssum + i * NSLOT;
            double focal = A[0] * inv;
            double edge  = A[1] * inv;
            double dsum  = 0.0;
            for (int bb = 0; bb < BB; ++bb)
                dsum += 2.0 * A[2 + bb] / (A[10 + bb] + 1e-10);
            double dice = 1.0 - dsum / (double)BB;
            loss += focal / sig0 + dice / sig1 + edge / sig2;
        }
        loss += (double)diff[0];
        loss += 0.5 * (log(sig0) + log(sig1) + log(sig2));
        out[0] = (float)loss;
    }
}

extern "C" void kernel_launch(void* const* d_in, const int* in_sizes, int n_in,
                              void* d_out, int out_size, void* d_ws, size_t ws_size,
                              hipStream_t stream)
{
    const float* pred   = (const float*)d_in[0]; // (2,8,2,1024,1024)
    const float* diss   = (const float*)d_in[1]; // (1,8,2,1024,1024)
    const int*   target = (const int*)  d_in[2]; // (8,1024,1024)
    const float* diff   = (const float*)d_in[3];
    const float* sigma  = (const float*)d_in[4];

    double* acc = (double*)d_ws;
    unsigned char* amap = (unsigned char*)d_ws + 16384;  // 8 MB byte map

    hipMemsetAsync(d_ws, 0, 16384, stream);

    dim3 gridA(WW / TWA, HH / THA, BB);   // (8, 64, 8)
    at_map_kernel<<<gridA, 256, 0, stream>>>(target, amap);

    stream_kernel<<<2048, 256, 0, stream>>>(pred, diss, amap, acc);

    finalize_kernel<<<1, 256, 0, stream>>>(acc, diff, sigma, (float*)d_out);
}

// Round 6
// 274.662 us; speedup vs baseline: 1.6874x; 1.0082x over previous
//
#include <hip/hip_runtime.h>
#include <math.h>

// Problem constants
#define BB 8
#define HH 1024
#define WW 1024
#define HW (1024*1024)

#define NCOPY 32
#define NSLOT 18       // per image: [0]=focal, [1]=edge, [2+b]=I_b, [10+b]=U_b
// acc layout: acc[(img*NSLOT + slot)*NCOPY + copy]
// d_ws layout: [0,13824) acc doubles; amap at byte offset 16384 (8 MB)

// ---------------- Pass A: target -> at-map (byte codes) ----------------
// code byte = (tbit << 7) | at29, where at29 = |29*t - cnt| in 0..29
#define TWA 128
#define THA 16
#define HALO_HA (THA + 6)   // 22
#define TSTRIDEA 136        // stored_col = halo_col + 1 (dword-aligned groups)

__global__ __launch_bounds__(256)
void at_map_kernel(const int* __restrict__ target,
                   unsigned char* __restrict__ amap)
{
    __shared__ unsigned char tileb[HALO_HA][TSTRIDEA];
    __shared__ unsigned char h5b[HALO_HA][TWA];
    __shared__ unsigned char h7b[HALO_HA][TWA];

    const int bx = blockIdx.x;   // 0..7
    const int by = blockIdx.y;   // 0..63
    const int b  = blockIdx.z;   // 0..7
    const int x0 = bx * TWA, y0 = by * THA;
    const int tid = threadIdx.x;

    // stage 1: target halo -> packed bytes
    const int* tgt_b = target + (size_t)b * HW;
    for (int ch = tid; ch < HALO_HA * 34; ch += 256) {
        int r = ch / 34;
        int m = ch - r * 34;
        int gy  = y0 - 3 + r;
        int gxb = x0 - 4 + 4 * m;    // stored cols 4m..4m+3
        unsigned pk = 0u;
        if (gy >= 0 && gy < HH) {
            if (gxb >= 0 && gxb + 3 < WW) {
                const int4 iv = *(const int4*)(tgt_b + (size_t)gy * WW + gxb);
                pk = (unsigned)iv.x | ((unsigned)iv.y << 8)
                   | ((unsigned)iv.z << 16) | ((unsigned)iv.w << 24);
            } else {
                #pragma unroll
                for (int j = 0; j < 4; ++j) {
                    int gx = gxb + j;
                    if (gx >= 0 && gx < WW)
                        pk |= ((unsigned)tgt_b[(size_t)gy * WW + gx]) << (8 * j);
                }
            }
        }
        *(unsigned*)&tileb[r][4 * m] = pk;
    }
    __syncthreads();

    // stage 2: horizontal 5/7-wide sums (byte lanes, no carry possible)
    for (int g = tid; g < HALO_HA * 32; g += 256) {
        int r  = g >> 5;
        int xg = (g & 31) << 2;
        const unsigned char* row = &tileb[r][0];
        unsigned d0 = *(const unsigned*)(row + xg);
        unsigned d1 = *(const unsigned*)(row + xg + 4);
        unsigned d2 = *(const unsigned*)(row + xg + 8);
        int s1 = (d0 >> 8) & 255, s2 = (d0 >> 16) & 255, s3 = (d0 >> 24) & 255;
        int s4 = d1 & 255, s5 = (d1 >> 8) & 255, s6 = (d1 >> 16) & 255, s7 = (d1 >> 24) & 255;
        int s8 = d2 & 255, s9 = (d2 >> 8) & 255, s10 = (d2 >> 16) & 255;
        int v5x = s2 + s3 + s4 + s5 + s6;
        int v5y = v5x - s2 + s7;
        int v5z = v5y - s3 + s8;
        int v5w = v5z - s4 + s9;
        int v7x = v5x + s1 + s7;
        int v7y = v5y + s2 + s8;
        int v7z = v5z + s3 + s9;
        int v7w = v5w + s4 + s10;
        *(unsigned*)&h5b[r][xg] = (unsigned)v5x | ((unsigned)v5y << 8)
                                | ((unsigned)v5z << 16) | ((unsigned)v5w << 24);
        *(unsigned*)&h7b[r][xg] = (unsigned)v7x | ((unsigned)v7y << 8)
                                | ((unsigned)v7z << 16) | ((unsigned)v7w << 24);
    }
    __syncthreads();

    // stage 3: per-pixel code bytes, 8 px/thread, dword stores
    const int x  = (tid & 31) * 4;
    const int gx = x0 + x;
    const int ty = tid >> 5;
    #pragma unroll
    for (int k = 0; k < 2; ++k) {
        const int r  = ty + 8 * k;      // 0..15
        const int gy = y0 + r;
        const unsigned tq  = *(const unsigned*)&tileb[r + 3][x + 4];
        const unsigned top = *(const unsigned*)&tileb[r    ][x + 4];
        const unsigned bot = *(const unsigned*)&tileb[r + 6][x + 4];
        const unsigned e1  = *(const unsigned*)&h5b[r + 1][x];
        const unsigned e2  = *(const unsigned*)&h5b[r + 2][x];
        const unsigned e3  = *(const unsigned*)&h7b[r + 3][x];
        const unsigned e4  = *(const unsigned*)&h5b[r + 4][x];
        const unsigned e5  = *(const unsigned*)&h5b[r + 5][x];
        const unsigned cnt = top + bot + e1 + e2 + e3 + e4 + e5;  // bytes <= 29

        unsigned code = 0u;
        #pragma unroll
        for (int j = 0; j < 4; ++j) {
            unsigned tbit = (tq >> (8 * j)) & 1u;
            int cj = (int)((cnt >> (8 * j)) & 0xffu);
            int a29 = tbit ? (29 - cj) : cj;      // |29*t - cnt|, 0..29
            code |= ((tbit << 7) | (unsigned)a29) << (8 * j);
        }
        *(unsigned*)(amap + (size_t)b * HW + (size_t)gy * WW + gx) = code;
    }
}

// ---------------- Pass B: streaming loss, clustered deep loads ----------------
#define NITER 4

__global__ __launch_bounds__(256, 3)
void stream_kernel(const float* __restrict__ pred,
                   const float* __restrict__ diss,
                   const unsigned char* __restrict__ amap,
                   double* __restrict__ acc)
{
    __shared__ float red[4][12];

    const int tid = threadIdx.x;
    const unsigned tg = blockIdx.x * 256u + (unsigned)tid;  // 0..524287
    const int b = (int)(tg >> 16);                          // uniform per block
    const unsigned lane = tg & 65535u;

    const float* p00 = pred + ((size_t)(0 * BB + b) * 2 + 0) * HW;
    const float* p01 = p00 + HW;
    const float* p10 = pred + ((size_t)(1 * BB + b) * 2 + 0) * HW;
    const float* p11 = p10 + HW;
    const float* q0  = diss + ((size_t)b * 2 + 0) * HW;
    const float* q1  = q0 + HW;
    const unsigned char* am = amap + (size_t)b * HW;

    // ---- issue ALL loads up front (24 dwordx4 + 4 dword), pinned ----
    float4 L00[NITER], L01[NITER], L10[NITER], L11[NITER], LW0[NITER], LW1[NITER];
    unsigned code[NITER];
    #pragma unroll
    for (int i = 0; i < NITER; ++i) {
        const size_t off = (size_t)lane * 4 + (size_t)i * (65536u * 4u); // px
        L00[i] = *(const float4*)(p00 + off);
        L01[i] = *(const float4*)(p01 + off);
        L10[i] = *(const float4*)(p10 + off);
        L11[i] = *(const float4*)(p11 + off);
        LW0[i] = *(const float4*)(q0  + off);
        LW1[i] = *(const float4*)(q1  + off);
        code[i] = *(const unsigned*)(am + off);
    }
    __builtin_amdgcn_sched_barrier(0);   // keep the load cluster intact

    float sf0=0.f, se0=0.f, si0=0.f, su0=0.f;
    float sf1=0.f, se1=0.f, si1=0.f, su1=0.f;
    float sf2=0.f, se2=0.f, si2=0.f, su2=0.f;

    #pragma unroll
    for (int i = 0; i < NITER; ++i) {
        #pragma unroll
        for (int j = 0; j < 4; ++j) {
            const unsigned cj   = (code[i] >> (8 * j)) & 0xffu;
            const unsigned tbit = cj >> 7;
            const float tf = (float)tbit;
            const float at = (float)(cj & 0x7fu) * (1.0f / 29.0f);
            // image 0 (softmax of 2 channels)
            {
                float a0 = ((const float*)&L00[i])[j], a1 = ((const float*)&L01[i])[j];
                float p1v = __builtin_amdgcn_rcpf(1.0f + __expf(a0 - a1));
                float pt  = tbit ? p1v : 1.0f - p1v;
                float lp  = __logf(pt + 1e-10f);
                sf0 -= lp; se0 -= lp * at; si0 += p1v * tf; su0 += p1v + tf;
            }
            // image 1
            {
                float a0 = ((const float*)&L10[i])[j], a1 = ((const float*)&L11[i])[j];
                float p1v = __builtin_amdgcn_rcpf(1.0f + __expf(a0 - a1));
                float pt  = tbit ? p1v : 1.0f - p1v;
                float lp  = __logf(pt + 1e-10f);
                sf1 -= lp; se1 -= lp * at; si1 += p1v * tf; su1 += p1v + tf;
            }
            // Diss (raw probs)
            {
                float d0 = ((const float*)&LW0[i])[j], d1 = ((const float*)&LW1[i])[j];
                float pt = tbit ? d1 : d0;
                float lp = __logf(pt + 1e-10f);
                sf2 -= lp; se2 -= lp * at; si2 += d1 * tf; su2 += d1 + tf;
            }
        }
    }

    // block reduction -> 12 f64 atomics
    float vals[12] = {sf0,se0,si0,su0, sf1,se1,si1,su1, sf2,se2,si2,su2};
    #pragma unroll
    for (int j = 0; j < 12; ++j) {
        float v = vals[j];
        #pragma unroll
        for (int s = 32; s > 0; s >>= 1) v += __shfl_down(v, s, 64);
        vals[j] = v;
    }
    const int wave = tid >> 6;
    const int lanew = tid & 63;
    if (lanew == 0) {
        #pragma unroll
        for (int j = 0; j < 12; ++j) red[wave][j] = vals[j];
    }
    __syncthreads();
    if (tid < 12) {
        double s = (double)red[0][tid] + (double)red[1][tid]
                 + (double)red[2][tid] + (double)red[3][tid];
        const int img  = tid >> 2;
        const int what = tid & 3;
        int slot;
        if      (what == 0) slot = 0;
        else if (what == 1) slot = 1;
        else if (what == 2) slot = 2 + b;
        else                slot = 10 + b;
        const int copy = blockIdx.x & (NCOPY - 1);
        unsafeAtomicAdd(acc + ((size_t)(img * NSLOT + slot) * NCOPY + copy), s);
    }
}

// ---------------- Pass C: parallel finalize ----------------
__global__ __launch_bounds__(256)
void finalize_kernel(const double* __restrict__ acc,
                     const float*  __restrict__ diff,
                     const float*  __restrict__ sigma,
                     float*        __restrict__ out)
{
    __shared__ double ssum[54];
    const int t = threadIdx.x;
    if (t < 216) {
        const int sl = t >> 2, part = t & 3;
        const double* p = acc + (size_t)sl * NCOPY + part * 8;
        double s = 0.0;
        #pragma unroll
        for (int j = 0; j < 8; ++j) s += p[j];
        s += __shfl_down(s, 1, 64);
        s += __shfl_down(s, 2, 64);
        if (part == 0) ssum[sl] = s;
    }
    __syncthreads();
    if (t == 0) {
        const double sig0 = (double)sigma[0] * (double)sigma[0];
        const double sig1 = (double)sigma[1] * (double)sigma[1];
        const double sig2 = (double)sigma[2] * (double)sigma[2];
        const double inv  = 1.0 / (double)((size_t)BB * HW);
        double loss = 0.0;
        for (int i = 0; i < 3; ++i) {
            const double* A = ssum + i * NSLOT;
            double focal = A[0] * inv;
            double edge  = A[1] * inv;
            double dsum  = 0.0;
            for (int bb = 0; bb < BB; ++bb)
                dsum += 2.0 * A[2 + bb] / (A[10 + bb] + 1e-10);
            double dice = 1.0 - dsum / (double)BB;
            loss += focal / sig0 + dice / sig1 + edge / sig2;
        }
        loss += (double)diff[0];
        loss += 0.5 * (log(sig0) + log(sig1) + log(sig2));
        out[0] = (float)loss;
    }
}

extern "C" void kernel_launch(void* const* d_in, const int* in_sizes, int n_in,
                              void* d_out, int out_size, void* d_ws, size_t ws_size,
                              hipStream_t stream)
{
    const float* pred   = (const float*)d_in[0]; // (2,8,2,1024,1024)
    const float* diss   = (const float*)d_in[1]; // (1,8,2,1024,1024)
    const int*   target = (const int*)  d_in[2]; // (8,1024,1024)
    const float* diff   = (const float*)d_in[3];
    const float* sigma  = (const float*)d_in[4];

    double* acc = (double*)d_ws;
    unsigned char* amap = (unsigned char*)d_ws + 16384;  // 8 MB byte map

    hipMemsetAsync(d_ws, 0, 16384, stream);

    dim3 gridA(WW / TWA, HH / THA, BB);   // (8, 64, 8)
    at_map_kernel<<<gridA, 256, 0, stream>>>(target, amap);

    stream_kernel<<<2048, 256, 0, stream>>>(pred, diss, amap, acc);

    finalize_kernel<<<1, 256, 0, stream>>>(acc, diff, sigma, (float*)d_out);
}